// Round 2
// baseline (470.279 us; speedup 1.0000x reference)
//
#include <hip/hip_runtime.h>
#include <stdint.h>

// Problem constants: B=4, T=2048, C=1024, H=16, D=64, M = B*T = 8192.
// Inputs are fp32 (per stub contract); output fp32. The np reference is
// bf16-emulated (round-0 max|ref|=3.8125 on bf16 grid, threshold 2% of max),
// so an internal bf16 MFMA pipeline is well within tolerance.

typedef __attribute__((ext_vector_type(8))) short bf16x8;   // MFMA A/B frag (4 VGPRs)
typedef __attribute__((ext_vector_type(8))) ushort u16x8;
typedef __attribute__((ext_vector_type(4))) float f32x4;    // MFMA C/D frag

__device__ __forceinline__ float bf2f(ushort u) {
  union { float f; uint32_t i; } c; c.i = ((uint32_t)u) << 16; return c.f;
}
__device__ __forceinline__ ushort f2bf(float f) {
  union { float f; uint32_t i; } c; c.f = f;
  uint32_t r = c.i + 0x7fffu + ((c.i >> 16) & 1u);  // RNE
  return (ushort)(r >> 16);
}

// ---------------------------------------------------------------------------
// fp32 -> bf16 elementwise (n divisible by 2048).
__global__ __launch_bounds__(256) void f32_to_bf16(const float* __restrict__ in,
                                                   ushort* __restrict__ out, int n) {
  const int i = (blockIdx.x * 256 + threadIdx.x) * 8;
  if (i + 8 > n) return;
  float4 a = *(const float4*)(in + i);
  float4 b = *(const float4*)(in + i + 4);
  u16x8 r;
  r[0] = f2bf(a.x); r[1] = f2bf(a.y); r[2] = f2bf(a.z); r[3] = f2bf(a.w);
  r[4] = f2bf(b.x); r[5] = f2bf(b.y); r[6] = f2bf(b.z); r[7] = f2bf(b.w);
  *(u16x8*)(out + i) = r;
}

// ---------------------------------------------------------------------------
// W (K x N, row-major fp32) -> Wt (N x K, row-major bf16). 32x32 LDS tiles.
__global__ __launch_bounds__(256) void transpose_f32_bf16(const float* __restrict__ W,
                                                          ushort* __restrict__ Wt) {
  __shared__ ushort tile[32][33];
  const int k0 = blockIdx.x * 32, n0 = blockIdx.y * 32;
  const int tx = threadIdx.x & 31, ty = threadIdx.x >> 5;  // 32 x 8
#pragma unroll
  for (int i = 0; i < 4; ++i)
    tile[ty + i * 8][tx] = f2bf(W[(size_t)(k0 + ty + i * 8) * 1024 + n0 + tx]);
  __syncthreads();
#pragma unroll
  for (int i = 0; i < 4; ++i)
    Wt[(size_t)(n0 + ty + i * 8) * 1024 + k0 + tx] = tile[tx][ty + i * 8];
}

// ---------------------------------------------------------------------------
// C[m,n] = sum_k A[m,k] * Bt[n,k] + bias[n].  A: MxK row-major bf16,
// Bt: NxK row-major bf16, bias fp32.  128x128 tile, BK=32, 4 waves each
// 64x64 (4x4 of 16x16x32 MFMA).  MODE 0: fp32 row-major [M,N];
// MODE 1: bf16 [B,H,T,D]; MODE 2: bf16 [B,H,D,T] (V, so PV B-frags are
// contiguous ds_read_b128).
template <int MODE>
__global__ __launch_bounds__(256) void gemm_bt(const ushort* __restrict__ A,
                                               const ushort* __restrict__ Bt,
                                               const float* __restrict__ bias,
                                               void* __restrict__ outp,
                                               int M, int N, int K) {
  __shared__ ushort As[128][40];  // +8 pad: 80B stride -> 2-way (free) bank alias
  __shared__ ushort Bs[128][40];
  const int tid = threadIdx.x;
  const int lane = tid & 63, wave = tid >> 6;
  const int quad = lane >> 4, l16 = lane & 15;
  const int wy = wave >> 1, wx = wave & 1;
  const int m0 = blockIdx.y * 128, n0 = blockIdx.x * 128;

  const f32x4 fzero = {0.f, 0.f, 0.f, 0.f};
  f32x4 acc[4][4];
#pragma unroll
  for (int i = 0; i < 4; ++i)
#pragma unroll
    for (int j = 0; j < 4; ++j) acc[i][j] = fzero;

  const int nk = K >> 5;
  for (int kt = 0; kt < nk; ++kt) {
    // stage global -> regs (16B/lane/chunk, 2 chunks per matrix)
    const int r0 = tid >> 2, k0 = (tid & 3) << 3;
    const int r1 = r0 + 64, k1 = k0;
    uint4 ra0 = *(const uint4*)(A + (size_t)(m0 + r0) * K + kt * 32 + k0);
    uint4 rb0 = *(const uint4*)(Bt + (size_t)(n0 + r0) * K + kt * 32 + k0);
    uint4 ra1 = *(const uint4*)(A + (size_t)(m0 + r1) * K + kt * 32 + k1);
    uint4 rb1 = *(const uint4*)(Bt + (size_t)(n0 + r1) * K + kt * 32 + k1);
    __syncthreads();  // previous iter's LDS reads done
    *(uint4*)&As[r0][k0] = ra0;
    *(uint4*)&Bs[r0][k0] = rb0;
    *(uint4*)&As[r1][k1] = ra1;
    *(uint4*)&Bs[r1][k1] = rb1;
    __syncthreads();

    bf16x8 af[4], bfr[4];
#pragma unroll
    for (int i = 0; i < 4; ++i)
      af[i] = *(const bf16x8*)&As[wy * 64 + i * 16 + l16][quad * 8];
#pragma unroll
    for (int j = 0; j < 4; ++j)
      bfr[j] = *(const bf16x8*)&Bs[wx * 64 + j * 16 + l16][quad * 8];
#pragma unroll
    for (int i = 0; i < 4; ++i)
#pragma unroll
      for (int j = 0; j < 4; ++j)
        acc[i][j] = __builtin_amdgcn_mfma_f32_16x16x32_bf16(af[i], bfr[j], acc[i][j], 0, 0, 0);
  }

  // epilogue: C/D layout row = quad*4+reg, col = lane&15 (m89-verified)
#pragma unroll
  for (int j = 0; j < 4; ++j) {
    const int col = n0 + wx * 64 + j * 16 + l16;
    const float bv = bias[col];
#pragma unroll
    for (int i = 0; i < 4; ++i) {
#pragma unroll
      for (int r = 0; r < 4; ++r) {
        const int row = m0 + wy * 64 + i * 16 + quad * 4 + r;
        const float v = acc[i][j][r] + bv;
        if (MODE == 0) {
          ((float*)outp)[(size_t)row * N + col] = v;
        } else {
          ushort* out = (ushort*)outp;
          const int b = row >> 11, t = row & 2047, h = col >> 6, d = col & 63;
          if (MODE == 1)
            out[(((size_t)(b * 16 + h) * 2048) + t) * 64 + d] = f2bf(v);
          else
            out[(((size_t)(b * 16 + h) * 64) + d) * 2048 + t] = f2bf(v);
        }
      }
    }
  }
}

// ---------------------------------------------------------------------------
// Flash attention, causal.  q,k: [BH][T][64] bf16; v: [BH][64][T] bf16;
// y: [B][T][C] bf16.  Block = 256 threads (4 waves); 128 Q rows per block
// (32 per wave); K/V tiles of 64 rows; online softmax per Q row.
__global__ __launch_bounds__(256) void attn_kernel(const ushort* __restrict__ q,
                                                   const ushort* __restrict__ k,
                                                   const ushort* __restrict__ v,
                                                   ushort* __restrict__ y) {
  const int T = 2048;
  const int bh = blockIdx.y;            // 0..63
  const int qt = blockIdx.x;            // 0..15
  const int qbase = qt * 128;
  const int tid = threadIdx.x;
  const int lane = tid & 63, wave = tid >> 6;
  const int quad = lane >> 4, l16 = lane & 15;

  __shared__ ushort Qs[128][72];        // 18 KB
  __shared__ ushort Ks[64][72];         //  9 KB
  __shared__ ushort Vs[64][72];         //  9 KB (Vs[d][s])
  __shared__ ushort Ps[4][32][72];      // 18 KB, per-wave P slab

  const ushort* qp = q + (size_t)bh * T * 64;
  const ushort* kp = k + (size_t)bh * T * 64;
  const ushort* vp = v + (size_t)bh * 64 * T;

  // stage Q tile (128 x 64)
#pragma unroll
  for (int it = 0; it < 4; ++it) {
    const int c = tid + it * 256;       // 1024 chunks of 8 bf16
    const int row = c >> 3, ko = (c & 7) * 8;
    *(uint4*)&Qs[row][ko] = *(const uint4*)(qp + (size_t)(qbase + row) * 64 + ko);
  }
  __syncthreads();

  bf16x8 aq[2][2];
#pragma unroll
  for (int i = 0; i < 2; ++i)
#pragma unroll
    for (int kk = 0; kk < 2; ++kk)
      aq[i][kk] = *(const bf16x8*)&Qs[wave * 32 + i * 16 + l16][kk * 32 + quad * 8];

  const f32x4 fzero = {0.f, 0.f, 0.f, 0.f};
  f32x4 acc_o[2][4];
  float mstate[2][4], lstate[2][4];
#pragma unroll
  for (int i = 0; i < 2; ++i)
#pragma unroll
    for (int r = 0; r < 4; ++r) { mstate[i][r] = -1e30f; lstate[i][r] = 0.f; }
#pragma unroll
  for (int i = 0; i < 2; ++i)
#pragma unroll
    for (int jd = 0; jd < 4; ++jd) acc_o[i][jd] = fzero;

  const int nkt = qt * 2 + 2;           // causal: only tiles touching the diagonal
  for (int kt = 0; kt < nkt; ++kt) {
    __syncthreads();                    // previous iter's Ks/Vs reads done
#pragma unroll
    for (int it = 0; it < 2; ++it) {
      const int c = tid + it * 256;     // 512 chunks of 8 bf16
      const int row = c >> 3, ko = (c & 7) * 8;
      *(uint4*)&Ks[row][ko] = *(const uint4*)(kp + (size_t)(kt * 64 + row) * 64 + ko);
      *(uint4*)&Vs[row][ko] = *(const uint4*)(vp + (size_t)row * T + kt * 64 + ko);
    }
    __syncthreads();

    // wave-uniform causal skip (this wave's rows all below this K tile)
    if (kt * 64 <= qbase + wave * 32 + 31) {
      // S = Q K^T: 2x4 tiles of 16x16
      f32x4 sacc[2][4];
#pragma unroll
      for (int i = 0; i < 2; ++i)
#pragma unroll
        for (int j = 0; j < 4; ++j) sacc[i][j] = fzero;
      bf16x8 bk[4][2];
#pragma unroll
      for (int j = 0; j < 4; ++j)
#pragma unroll
        for (int kk = 0; kk < 2; ++kk)
          bk[j][kk] = *(const bf16x8*)&Ks[j * 16 + l16][kk * 32 + quad * 8];
#pragma unroll
      for (int i = 0; i < 2; ++i)
#pragma unroll
        for (int j = 0; j < 4; ++j)
#pragma unroll
          for (int kk = 0; kk < 2; ++kk)
            sacc[i][j] = __builtin_amdgcn_mfma_f32_16x16x32_bf16(aq[i][kk], bk[j][kk], sacc[i][j], 0, 0, 0);

      // online softmax per row (row = quad*4 + r within each 16-tile)
#pragma unroll
      for (int i = 0; i < 2; ++i) {
#pragma unroll
        for (int r = 0; r < 4; ++r) {
          const int trow = qbase + wave * 32 + i * 16 + quad * 4 + r;
          float sv[4];
          float rmax = -1e30f;
#pragma unroll
          for (int j = 0; j < 4; ++j) {
            const int scol = kt * 64 + j * 16 + l16;
            float xv = sacc[i][j][r] * 0.125f;       // 1/sqrt(64)
            if (scol > trow) xv = -1e30f;            // causal mask
            sv[j] = xv;
            rmax = fmaxf(rmax, xv);
          }
#pragma unroll
          for (int off = 1; off < 16; off <<= 1)
            rmax = fmaxf(rmax, __shfl_xor(rmax, off, 64));
          const float mnew = fmaxf(mstate[i][r], rmax);
          const float alpha = __expf(mstate[i][r] - mnew);
          float rsum = 0.f;
#pragma unroll
          for (int j = 0; j < 4; ++j) {
            const float p = __expf(sv[j] - mnew);
            sv[j] = p;
            rsum += p;
          }
#pragma unroll
          for (int off = 1; off < 16; off <<= 1)
            rsum += __shfl_xor(rsum, off, 64);
          lstate[i][r] = lstate[i][r] * alpha + rsum;
          mstate[i][r] = mnew;
#pragma unroll
          for (int jd = 0; jd < 4; ++jd) acc_o[i][jd][r] *= alpha;
          // P: C-layout -> LDS (per-wave slab; no cross-wave barrier needed)
#pragma unroll
          for (int j = 0; j < 4; ++j)
            Ps[wave][i * 16 + quad * 4 + r][j * 16 + l16] = f2bf(sv[j]);
        }
      }

      // O += P V  (P from LDS in A-layout; V^T gives contiguous B-frags)
      bf16x8 ap[2][2], bv[4][2];
#pragma unroll
      for (int i = 0; i < 2; ++i)
#pragma unroll
        for (int kk = 0; kk < 2; ++kk)
          ap[i][kk] = *(const bf16x8*)&Ps[wave][i * 16 + l16][kk * 32 + quad * 8];
#pragma unroll
      for (int jd = 0; jd < 4; ++jd)
#pragma unroll
        for (int kk = 0; kk < 2; ++kk)
          bv[jd][kk] = *(const bf16x8*)&Vs[jd * 16 + l16][kk * 32 + quad * 8];
#pragma unroll
      for (int i = 0; i < 2; ++i)
#pragma unroll
        for (int jd = 0; jd < 4; ++jd)
#pragma unroll
          for (int kk = 0; kk < 2; ++kk)
            acc_o[i][jd] = __builtin_amdgcn_mfma_f32_16x16x32_bf16(ap[i][kk], bv[jd][kk], acc_o[i][jd], 0, 0, 0);
    }
  }

  // epilogue: y[b][t][h*64+d] = O / l
  const int b = bh >> 4, h = bh & 15;
#pragma unroll
  for (int i = 0; i < 2; ++i) {
#pragma unroll
    for (int r = 0; r < 4; ++r) {
      const int t = qbase + wave * 32 + i * 16 + quad * 4 + r;
      const float inv = 1.0f / lstate[i][r];
#pragma unroll
      for (int jd = 0; jd < 4; ++jd) {
        const int d = jd * 16 + l16;
        y[((size_t)(b * 2048 + t)) * 1024 + h * 64 + d] = f2bf(acc_o[i][jd][r] * inv);
      }
    }
  }
}

// ---------------------------------------------------------------------------
extern "C" void kernel_launch(void* const* d_in, const int* in_sizes, int n_in,
                              void* d_out, int out_size, void* d_ws, size_t ws_size,
                              hipStream_t stream) {
  const float* x  = (const float*)d_in[0];
  const float* Wq = (const float*)d_in[1];
  const float* bq = (const float*)d_in[2];
  const float* Wk = (const float*)d_in[3];
  const float* bk = (const float*)d_in[4];
  const float* Wv = (const float*)d_in[5];
  const float* bv = (const float*)d_in[6];
  const float* Wp = (const float*)d_in[7];
  const float* bp = (const float*)d_in[8];

  ushort* ws  = (ushort*)d_ws;          // element (ushort) offsets
  ushort* wqt = ws;                     // 1M elems each
  ushort* wkt = wqt + (size_t)1024 * 1024;
  ushort* wvt = wkt + (size_t)1024 * 1024;
  ushort* wpt = wvt + (size_t)1024 * 1024;
  ushort* xb  = wpt + (size_t)1024 * 1024;   // 8M elems each
  ushort* q   = xb + (size_t)8192 * 1024;
  ushort* kk  = q  + (size_t)8192 * 1024;
  ushort* vv  = kk + (size_t)8192 * 1024;
  ushort* y   = vv + (size_t)8192 * 1024;    // total 88 MB

  const dim3 tb(256);
  hipLaunchKernelGGL(f32_to_bf16, dim3(4096), tb, 0, stream, x, xb, 8192 * 1024);
  const dim3 tg(32, 32);
  hipLaunchKernelGGL(transpose_f32_bf16, tg, tb, 0, stream, Wq, wqt);
  hipLaunchKernelGGL(transpose_f32_bf16, tg, tb, 0, stream, Wk, wkt);
  hipLaunchKernelGGL(transpose_f32_bf16, tg, tb, 0, stream, Wv, wvt);
  hipLaunchKernelGGL(transpose_f32_bf16, tg, tb, 0, stream, Wp, wpt);

  const dim3 gg(8, 64);                 // N/128, M/128
  hipLaunchKernelGGL((gemm_bt<1>), gg, tb, 0, stream, xb, wqt, bq, (void*)q,  8192, 1024, 1024);
  hipLaunchKernelGGL((gemm_bt<1>), gg, tb, 0, stream, xb, wkt, bk, (void*)kk, 8192, 1024, 1024);
  hipLaunchKernelGGL((gemm_bt<2>), gg, tb, 0, stream, xb, wvt, bv, (void*)vv, 8192, 1024, 1024);

  const dim3 ag(16, 64);                // T/128, B*H
  hipLaunchKernelGGL(attn_kernel, ag, tb, 0, stream, q, kk, vv, y);

  hipLaunchKernelGGL((gemm_bt<0>), gg, tb, 0, stream, y, wpt, bp, d_out, 8192, 1024, 1024);
}

// Round 3
// 411.429 us; speedup vs baseline: 1.1430x; 1.1430x over previous
//
#include <hip/hip_runtime.h>
#include <stdint.h>

// Problem constants: B=4, T=2048, C=1024, H=16, D=64, M = B*T = 8192.
// Inputs fp32, output fp32; internal pipeline bf16 MFMA (passed R2 with
// absmax 0.0156 vs threshold 0.076).

typedef __attribute__((ext_vector_type(8))) short bf16x8;   // MFMA A/B frag (4 VGPRs)
typedef __attribute__((ext_vector_type(8))) ushort u16x8;
typedef __attribute__((ext_vector_type(4))) float f32x4;    // MFMA C/D frag

__device__ __forceinline__ float bf2f(ushort u) {
  union { float f; uint32_t i; } c; c.i = ((uint32_t)u) << 16; return c.f;
}
__device__ __forceinline__ ushort f2bf(float f) {
  union { float f; uint32_t i; } c; c.f = f;
  uint32_t r = c.i + 0x7fffu + ((c.i >> 16) & 1u);  // RNE
  return (ushort)(r >> 16);
}
__device__ __forceinline__ uint32_t pack2bf(float lo, float hi) {
  return (uint32_t)f2bf(lo) | ((uint32_t)f2bf(hi) << 16);
}

// ---------------------------------------------------------------------------
// fp32 -> bf16 elementwise (n divisible by 2048).
__global__ __launch_bounds__(256) void f32_to_bf16(const float* __restrict__ in,
                                                   ushort* __restrict__ out, int n) {
  const int i = (blockIdx.x * 256 + threadIdx.x) * 8;
  if (i + 8 > n) return;
  float4 a = *(const float4*)(in + i);
  float4 b = *(const float4*)(in + i + 4);
  u16x8 r;
  r[0] = f2bf(a.x); r[1] = f2bf(a.y); r[2] = f2bf(a.z); r[3] = f2bf(a.w);
  r[4] = f2bf(b.x); r[5] = f2bf(b.y); r[6] = f2bf(b.z); r[7] = f2bf(b.w);
  *(u16x8*)(out + i) = r;
}

// ---------------------------------------------------------------------------
// W (K x N, row-major fp32) -> Wt (N x K, row-major bf16). 32x32 LDS tiles.
__global__ __launch_bounds__(256) void transpose_f32_bf16(const float* __restrict__ W,
                                                          ushort* __restrict__ Wt) {
  __shared__ ushort tile[32][33];
  const int k0 = blockIdx.x * 32, n0 = blockIdx.y * 32;
  const int tx = threadIdx.x & 31, ty = threadIdx.x >> 5;  // 32 x 8
#pragma unroll
  for (int i = 0; i < 4; ++i)
    tile[ty + i * 8][tx] = f2bf(W[(size_t)(k0 + ty + i * 8) * 1024 + n0 + tx]);
  __syncthreads();
#pragma unroll
  for (int i = 0; i < 4; ++i)
    Wt[(size_t)(n0 + ty + i * 8) * 1024 + k0 + tx] = tile[tx][ty + i * 8];
}

// ---------------------------------------------------------------------------
// C[m,n] = sum_k A[m,k] * Bt[n,k] + bias[n].  128x128 tile, BK=32, 4 waves.
// MODE 0: fp32 [M,N]; MODE 1: bf16 [B,H,T,D]; MODE 2: bf16 [B,H,D,T].
template <int MODE>
__global__ __launch_bounds__(256) void gemm_bt(const ushort* __restrict__ A,
                                               const ushort* __restrict__ Bt,
                                               const float* __restrict__ bias,
                                               void* __restrict__ outp,
                                               int M, int N, int K) {
  __shared__ ushort As[128][40];  // +8 pad: 80B stride -> 2-way (free) bank alias
  __shared__ ushort Bs[128][40];
  const int tid = threadIdx.x;
  const int lane = tid & 63, wave = tid >> 6;
  const int quad = lane >> 4, l16 = lane & 15;
  const int wy = wave >> 1, wx = wave & 1;
  const int m0 = blockIdx.y * 128, n0 = blockIdx.x * 128;

  const f32x4 fzero = {0.f, 0.f, 0.f, 0.f};
  f32x4 acc[4][4];
#pragma unroll
  for (int i = 0; i < 4; ++i)
#pragma unroll
    for (int j = 0; j < 4; ++j) acc[i][j] = fzero;

  const int nk = K >> 5;
  for (int kt = 0; kt < nk; ++kt) {
    const int r0 = tid >> 2, k0 = (tid & 3) << 3;
    const int r1 = r0 + 64, k1 = k0;
    uint4 ra0 = *(const uint4*)(A + (size_t)(m0 + r0) * K + kt * 32 + k0);
    uint4 rb0 = *(const uint4*)(Bt + (size_t)(n0 + r0) * K + kt * 32 + k0);
    uint4 ra1 = *(const uint4*)(A + (size_t)(m0 + r1) * K + kt * 32 + k1);
    uint4 rb1 = *(const uint4*)(Bt + (size_t)(n0 + r1) * K + kt * 32 + k1);
    __syncthreads();
    *(uint4*)&As[r0][k0] = ra0;
    *(uint4*)&Bs[r0][k0] = rb0;
    *(uint4*)&As[r1][k1] = ra1;
    *(uint4*)&Bs[r1][k1] = rb1;
    __syncthreads();

    bf16x8 af[4], bfr[4];
#pragma unroll
    for (int i = 0; i < 4; ++i)
      af[i] = *(const bf16x8*)&As[wy * 64 + i * 16 + l16][quad * 8];
#pragma unroll
    for (int j = 0; j < 4; ++j)
      bfr[j] = *(const bf16x8*)&Bs[wx * 64 + j * 16 + l16][quad * 8];
#pragma unroll
    for (int i = 0; i < 4; ++i)
#pragma unroll
      for (int j = 0; j < 4; ++j)
        acc[i][j] = __builtin_amdgcn_mfma_f32_16x16x32_bf16(af[i], bfr[j], acc[i][j], 0, 0, 0);
  }

  // epilogue: C/D layout row = quad*4+reg, col = lane&15
#pragma unroll
  for (int j = 0; j < 4; ++j) {
    const int col = n0 + wx * 64 + j * 16 + l16;
    const float bv = bias[col];
#pragma unroll
    for (int i = 0; i < 4; ++i) {
#pragma unroll
      for (int r = 0; r < 4; ++r) {
        const int row = m0 + wy * 64 + i * 16 + quad * 4 + r;
        const float v = acc[i][j][r] + bv;
        if (MODE == 0) {
          ((float*)outp)[(size_t)row * N + col] = v;
        } else {
          ushort* out = (ushort*)outp;
          const int b = row >> 11, t = row & 2047, h = col >> 6, d = col & 63;
          if (MODE == 1)
            out[(((size_t)(b * 16 + h) * 2048) + t) * 64 + d] = f2bf(v);
          else
            out[(((size_t)(b * 16 + h) * 64) + d) * 2048 + t] = f2bf(v);
        }
      }
    }
  }
}

// ---------------------------------------------------------------------------
// Flash attention, causal.  q,k: [BH][T][64] bf16; v: [BH][64][T] bf16 (=V^T);
// y: [B][T][C] bf16.  S^T = K Q^T formulation: each lane owns one Q row per
// 16-tile (t = l16), so softmax reductions are 2 shuffles; P^T goes to the
// PV B-operand via register shuffles (no LDS round trip).  O^T = V^T P^T.
__global__ __launch_bounds__(256, 4) void attn_kernel(const ushort* __restrict__ q,
                                                      const ushort* __restrict__ k,
                                                      const ushort* __restrict__ v,
                                                      ushort* __restrict__ y) {
  const int T = 2048;
  const int bh = blockIdx.y;            // 0..63
  const int qt = ((int)blockIdx.x + 4 * ((int)blockIdx.y >> 4)) & 15;  // CU load balance
  const int qbase = qt * 128;
  const int tid = threadIdx.x;
  const int lane = tid & 63, wave = tid >> 6;
  const int quad = lane >> 4, l16 = lane & 15;

  __shared__ ushort Qs[128][72];        // 18 KB
  __shared__ ushort Ks[64][72];         //  9 KB
  __shared__ ushort Vs[64][72];         //  9 KB (Vs[d][s])

  const ushort* qp = q + (size_t)bh * T * 64;
  const ushort* kp = k + (size_t)bh * T * 64;
  const ushort* vp = v + (size_t)bh * 64 * T;

  // stage Q tile (128 x 64)
#pragma unroll
  for (int it = 0; it < 4; ++it) {
    const int c = tid + it * 256;
    const int row = c >> 3, ko = (c & 7) * 8;
    *(uint4*)&Qs[row][ko] = *(const uint4*)(qp + (size_t)(qbase + row) * 64 + ko);
  }
  __syncthreads();

  // Q as B-operand frags (lane n=t=l16, k contiguous)
  bf16x8 aq[2][2];
#pragma unroll
  for (int i = 0; i < 2; ++i)
#pragma unroll
    for (int kk = 0; kk < 2; ++kk)
      aq[i][kk] = *(const bf16x8*)&Qs[wave * 32 + i * 16 + l16][kk * 32 + quad * 8];

  const f32x4 fzero = {0.f, 0.f, 0.f, 0.f};
  f32x4 acc_o[2][4];                    // O^T: [i-tile][jd], rows d=quad*4+r, col t=l16
  float mstate[2], lstate[2];
#pragma unroll
  for (int i = 0; i < 2; ++i) {
    mstate[i] = -1e30f; lstate[i] = 0.f;
#pragma unroll
    for (int jd = 0; jd < 4; ++jd) acc_o[i][jd] = fzero;
  }

  const int trow0 = qbase + wave * 32;
  const float SC = 0.125f * 1.4426950408889634f;  // (1/sqrt(64)) * log2(e)
  const int nkt = qt * 2 + 2;

  for (int kt = 0; kt < nkt; ++kt) {
    __syncthreads();
#pragma unroll
    for (int it = 0; it < 2; ++it) {
      const int c = tid + it * 256;
      const int row = c >> 3, ko = (c & 7) * 8;
      *(uint4*)&Ks[row][ko] = *(const uint4*)(kp + (size_t)(kt * 64 + row) * 64 + ko);
      *(uint4*)&Vs[row][ko] = *(const uint4*)(vp + (size_t)row * T + kt * 64 + ko);
    }
    __syncthreads();

    if (kt * 64 > trow0 + 31) continue;  // wave fully above diagonal for this K tile

    // K as A-operand frags (lane m=s=l16, k contiguous)
    bf16x8 ak[4][2];
#pragma unroll
    for (int j = 0; j < 4; ++j)
#pragma unroll
      for (int kk = 0; kk < 2; ++kk)
        ak[j][kk] = *(const bf16x8*)&Ks[j * 16 + l16][kk * 32 + quad * 8];

#pragma unroll
    for (int i = 0; i < 2; ++i) {
      const int tmin = trow0 + i * 16;
      if (kt * 64 > tmin + 15) continue;       // i-tile fully masked (wave-uniform)
      const int tglob = tmin + l16;            // this lane's Q row

      // S^T tile: D[m = s_local = j*16+quad*4+r][n = t = l16]
      f32x4 st[4];
#pragma unroll
      for (int j = 0; j < 4; ++j) st[j] = fzero;
#pragma unroll
      for (int j = 0; j < 4; ++j)
#pragma unroll
        for (int kk = 0; kk < 2; ++kk)
          st[j] = __builtin_amdgcn_mfma_f32_16x16x32_bf16(ak[j][kk], aq[i][kk], st[j], 0, 0, 0);

      // softmax over s (log2 domain): lane owns row t; 16 s-values in-lane
      float sv[16];
      float mp = -1e30f;
      const bool needmask = (kt * 64 + 63 > tmin);  // wave-uniform
      if (needmask) {
#pragma unroll
        for (int j = 0; j < 4; ++j)
#pragma unroll
          for (int r = 0; r < 4; ++r) {
            const int sg = kt * 64 + j * 16 + quad * 4 + r;
            float xv = st[j][r] * SC;
            if (sg > tglob) xv = -1e30f;
            sv[j * 4 + r] = xv;
            mp = fmaxf(mp, xv);
          }
      } else {
#pragma unroll
        for (int j = 0; j < 4; ++j)
#pragma unroll
          for (int r = 0; r < 4; ++r) {
            const float xv = st[j][r] * SC;
            sv[j * 4 + r] = xv;
            mp = fmaxf(mp, xv);
          }
      }
      mp = fmaxf(mp, __shfl_xor(mp, 16, 64));
      mp = fmaxf(mp, __shfl_xor(mp, 32, 64));
      const float mnew = fmaxf(mstate[i], mp);
      const float alpha = exp2f(mstate[i] - mnew);
      mstate[i] = mnew;
      float rs = 0.f;
#pragma unroll
      for (int e = 0; e < 16; ++e) {
        const float p = exp2f(sv[e] - mnew);
        sv[e] = p;
        rs += p;
      }
      rs += __shfl_xor(rs, 16, 64);
      rs += __shfl_xor(rs, 32, 64);
      lstate[i] = lstate[i] * alpha + rs;
#pragma unroll
      for (int jd = 0; jd < 4; ++jd) acc_o[i][jd] *= alpha;

      // pack P^T rows to bf16 pairs: pk[j][0]=(r0,r1), pk[j][1]=(r2,r3)
      uint32_t pk[4][2];
#pragma unroll
      for (int j = 0; j < 4; ++j) {
        pk[j][0] = pack2bf(sv[j * 4 + 0], sv[j * 4 + 1]);
        pk[j][1] = pack2bf(sv[j * 4 + 2], sv[j * 4 + 3]);
      }

      // build PV B-operand frags: lane (quad,l16) needs P^T[s=kk*32+quad*8+e][t=l16]
      // source lane L = src_quad*16 + l16, src_quad = (quad&1)*2 (+1), j_src = 2kk+(quad>>1)
      union BU { uint32_t w[4]; bf16x8 h; } bu[2];
      const int L0 = ((quad & 1) << 5) + l16;  // (quad&1)*2*16 + l16
      const int L1 = L0 + 16;
#pragma unroll
      for (int kk = 0; kk < 2; ++kk) {
        const int jA = 2 * kk, jB = 2 * kk + 1;
        uint32_t a0 = (uint32_t)__shfl((int)pk[jA][0], L0, 64);
        uint32_t b0 = (uint32_t)__shfl((int)pk[jB][0], L0, 64);
        uint32_t a1 = (uint32_t)__shfl((int)pk[jA][1], L0, 64);
        uint32_t b1 = (uint32_t)__shfl((int)pk[jB][1], L0, 64);
        uint32_t a2 = (uint32_t)__shfl((int)pk[jA][0], L1, 64);
        uint32_t b2 = (uint32_t)__shfl((int)pk[jB][0], L1, 64);
        uint32_t a3 = (uint32_t)__shfl((int)pk[jA][1], L1, 64);
        uint32_t b3 = (uint32_t)__shfl((int)pk[jB][1], L1, 64);
        const bool lo = (quad < 2);
        bu[kk].w[0] = lo ? a0 : b0;
        bu[kk].w[1] = lo ? a1 : b1;
        bu[kk].w[2] = lo ? a2 : b2;
        bu[kk].w[3] = lo ? a3 : b3;
      }

      // O^T += V^T P^T  (V^T A-frags straight from Vs[d][s])
#pragma unroll
      for (int jd = 0; jd < 4; ++jd) {
        bf16x8 av0 = *(const bf16x8*)&Vs[jd * 16 + l16][quad * 8];
        bf16x8 av1 = *(const bf16x8*)&Vs[jd * 16 + l16][32 + quad * 8];
        acc_o[i][jd] = __builtin_amdgcn_mfma_f32_16x16x32_bf16(av0, bu[0].h, acc_o[i][jd], 0, 0, 0);
        acc_o[i][jd] = __builtin_amdgcn_mfma_f32_16x16x32_bf16(av1, bu[1].h, acc_o[i][jd], 0, 0, 0);
      }
    }
  }

  // epilogue: O^T C-layout: d = jd*16 + quad*4 + r, t = trow0 + i*16 + l16
  const int b = bh >> 4, h = bh & 15;
#pragma unroll
  for (int i = 0; i < 2; ++i) {
    const int t = trow0 + i * 16 + l16;
    const float inv = 1.0f / lstate[i];
#pragma unroll
    for (int jd = 0; jd < 4; ++jd) {
      uint2 w;
      w.x = pack2bf(acc_o[i][jd][0] * inv, acc_o[i][jd][1] * inv);
      w.y = pack2bf(acc_o[i][jd][2] * inv, acc_o[i][jd][3] * inv);
      *(uint2*)&y[((size_t)(b * 2048 + t)) * 1024 + h * 64 + jd * 16 + quad * 4] = w;
    }
  }
}

// ---------------------------------------------------------------------------
extern "C" void kernel_launch(void* const* d_in, const int* in_sizes, int n_in,
                              void* d_out, int out_size, void* d_ws, size_t ws_size,
                              hipStream_t stream) {
  const float* x  = (const float*)d_in[0];
  const float* Wq = (const float*)d_in[1];
  const float* bq = (const float*)d_in[2];
  const float* Wk = (const float*)d_in[3];
  const float* bk = (const float*)d_in[4];
  const float* Wv = (const float*)d_in[5];
  const float* bv = (const float*)d_in[6];
  const float* Wp = (const float*)d_in[7];
  const float* bp = (const float*)d_in[8];

  ushort* ws  = (ushort*)d_ws;
  ushort* wqt = ws;
  ushort* wkt = wqt + (size_t)1024 * 1024;
  ushort* wvt = wkt + (size_t)1024 * 1024;
  ushort* wpt = wvt + (size_t)1024 * 1024;
  ushort* xb  = wpt + (size_t)1024 * 1024;
  ushort* q   = xb + (size_t)8192 * 1024;
  ushort* kk  = q  + (size_t)8192 * 1024;
  ushort* vv  = kk + (size_t)8192 * 1024;
  ushort* y   = vv + (size_t)8192 * 1024;

  const dim3 tb(256);
  hipLaunchKernelGGL(f32_to_bf16, dim3(4096), tb, 0, stream, x, xb, 8192 * 1024);
  const dim3 tg(32, 32);
  hipLaunchKernelGGL(transpose_f32_bf16, tg, tb, 0, stream, Wq, wqt);
  hipLaunchKernelGGL(transpose_f32_bf16, tg, tb, 0, stream, Wk, wkt);
  hipLaunchKernelGGL(transpose_f32_bf16, tg, tb, 0, stream, Wv, wvt);
  hipLaunchKernelGGL(transpose_f32_bf16, tg, tb, 0, stream, Wp, wpt);

  const dim3 gg(8, 64);                 // N/128, M/128
  hipLaunchKernelGGL((gemm_bt<1>), gg, tb, 0, stream, xb, wqt, bq, (void*)q,  8192, 1024, 1024);
  hipLaunchKernelGGL((gemm_bt<1>), gg, tb, 0, stream, xb, wkt, bk, (void*)kk, 8192, 1024, 1024);
  hipLaunchKernelGGL((gemm_bt<2>), gg, tb, 0, stream, xb, wvt, bv, (void*)vv, 8192, 1024, 1024);

  const dim3 ag(16, 64);                // T/128, B*H
  hipLaunchKernelGGL(attn_kernel, ag, tb, 0, stream, q, kk, vv, y);

  hipLaunchKernelGGL((gemm_bt<0>), gg, tb, 0, stream, y, wpt, bp, d_out, 8192, 1024, 1024);
}

// Round 4
// 385.972 us; speedup vs baseline: 1.2184x; 1.0660x over previous
//
#include <hip/hip_runtime.h>
#include <stdint.h>

// Problem constants: B=4, T=2048, C=1024, H=16, D=64, M = B*T = 8192.
// Inputs fp32, output fp32; internal pipeline bf16 MFMA (absmax 0.0156 vs
// threshold 0.076 in R2/R3).

typedef __attribute__((ext_vector_type(8))) short bf16x8;   // MFMA A/B frag (4 VGPRs)
typedef __attribute__((ext_vector_type(8))) ushort u16x8;
typedef __attribute__((ext_vector_type(4))) float f32x4;    // MFMA C/D frag

__device__ __forceinline__ float bf2f(ushort u) {
  union { float f; uint32_t i; } c; c.i = ((uint32_t)u) << 16; return c.f;
}
__device__ __forceinline__ ushort f2bf(float f) {
  union { float f; uint32_t i; } c; c.f = f;
  uint32_t r = c.i + 0x7fffu + ((c.i >> 16) & 1u);  // RNE
  return (ushort)(r >> 16);
}
__device__ __forceinline__ uint32_t pack2bf(float lo, float hi) {
  return (uint32_t)f2bf(lo) | ((uint32_t)f2bf(hi) << 16);
}

// ---------------------------------------------------------------------------
// fp32 -> bf16 elementwise (n divisible by 2048).
__global__ __launch_bounds__(256) void f32_to_bf16(const float* __restrict__ in,
                                                   ushort* __restrict__ out, int n) {
  const int i = (blockIdx.x * 256 + threadIdx.x) * 8;
  if (i + 8 > n) return;
  float4 a = *(const float4*)(in + i);
  float4 b = *(const float4*)(in + i + 4);
  u16x8 r;
  r[0] = f2bf(a.x); r[1] = f2bf(a.y); r[2] = f2bf(a.z); r[3] = f2bf(a.w);
  r[4] = f2bf(b.x); r[5] = f2bf(b.y); r[6] = f2bf(b.z); r[7] = f2bf(b.w);
  *(u16x8*)(out + i) = r;
}

// ---------------------------------------------------------------------------
// W (K x N, row-major fp32) -> Wt (N x K, row-major bf16). 32x32 LDS tiles.
__global__ __launch_bounds__(256) void transpose_f32_bf16(const float* __restrict__ W,
                                                          ushort* __restrict__ Wt) {
  __shared__ ushort tile[32][33];
  const int k0 = blockIdx.x * 32, n0 = blockIdx.y * 32;
  const int tx = threadIdx.x & 31, ty = threadIdx.x >> 5;  // 32 x 8
#pragma unroll
  for (int i = 0; i < 4; ++i)
    tile[ty + i * 8][tx] = f2bf(W[(size_t)(k0 + ty + i * 8) * 1024 + n0 + tx]);
  __syncthreads();
#pragma unroll
  for (int i = 0; i < 4; ++i)
    Wt[(size_t)(n0 + ty + i * 8) * 1024 + k0 + tx] = tile[tx][ty + i * 8];
}

// ---------------------------------------------------------------------------
// C[m,n] = sum_k A[m,k] * Bt[n,k] + bias[n].  128x128 tile, BK=32, 4 waves.
// MODE 0: fp32 [M,N]; MODE 1: bf16 [B,H,T,D]; MODE 2: bf16 [B,H,D,T].
template <int MODE>
__global__ __launch_bounds__(256) void gemm_bt(const ushort* __restrict__ A,
                                               const ushort* __restrict__ Bt,
                                               const float* __restrict__ bias,
                                               void* __restrict__ outp,
                                               int M, int N, int K) {
  __shared__ ushort As[128][40];  // +8 pad: 80B stride -> 2-way (free) bank alias
  __shared__ ushort Bs[128][40];
  const int tid = threadIdx.x;
  const int lane = tid & 63, wave = tid >> 6;
  const int quad = lane >> 4, l16 = lane & 15;
  const int wy = wave >> 1, wx = wave & 1;
  const int m0 = blockIdx.y * 128, n0 = blockIdx.x * 128;

  const f32x4 fzero = {0.f, 0.f, 0.f, 0.f};
  f32x4 acc[4][4];
#pragma unroll
  for (int i = 0; i < 4; ++i)
#pragma unroll
    for (int j = 0; j < 4; ++j) acc[i][j] = fzero;

  const int nk = K >> 5;
  for (int kt = 0; kt < nk; ++kt) {
    const int r0 = tid >> 2, k0 = (tid & 3) << 3;
    const int r1 = r0 + 64, k1 = k0;
    uint4 ra0 = *(const uint4*)(A + (size_t)(m0 + r0) * K + kt * 32 + k0);
    uint4 rb0 = *(const uint4*)(Bt + (size_t)(n0 + r0) * K + kt * 32 + k0);
    uint4 ra1 = *(const uint4*)(A + (size_t)(m0 + r1) * K + kt * 32 + k1);
    uint4 rb1 = *(const uint4*)(Bt + (size_t)(n0 + r1) * K + kt * 32 + k1);
    __syncthreads();
    *(uint4*)&As[r0][k0] = ra0;
    *(uint4*)&Bs[r0][k0] = rb0;
    *(uint4*)&As[r1][k1] = ra1;
    *(uint4*)&Bs[r1][k1] = rb1;
    __syncthreads();

    bf16x8 af[4], bfr[4];
#pragma unroll
    for (int i = 0; i < 4; ++i)
      af[i] = *(const bf16x8*)&As[wy * 64 + i * 16 + l16][quad * 8];
#pragma unroll
    for (int j = 0; j < 4; ++j)
      bfr[j] = *(const bf16x8*)&Bs[wx * 64 + j * 16 + l16][quad * 8];
#pragma unroll
    for (int i = 0; i < 4; ++i)
#pragma unroll
      for (int j = 0; j < 4; ++j)
        acc[i][j] = __builtin_amdgcn_mfma_f32_16x16x32_bf16(af[i], bfr[j], acc[i][j], 0, 0, 0);
  }

  // epilogue: C/D layout row = quad*4+reg, col = lane&15
#pragma unroll
  for (int j = 0; j < 4; ++j) {
    const int col = n0 + wx * 64 + j * 16 + l16;
    const float bv = bias[col];
#pragma unroll
    for (int i = 0; i < 4; ++i) {
#pragma unroll
      for (int r = 0; r < 4; ++r) {
        const int row = m0 + wy * 64 + i * 16 + quad * 4 + r;
        const float v = acc[i][j][r] + bv;
        if (MODE == 0) {
          ((float*)outp)[(size_t)row * N + col] = v;
        } else {
          ushort* out = (ushort*)outp;
          const int b = row >> 11, t = row & 2047, h = col >> 6, d = col & 63;
          if (MODE == 1)
            out[(((size_t)(b * 16 + h) * 2048) + t) * 64 + d] = f2bf(v);
          else
            out[(((size_t)(b * 16 + h) * 64) + d) * 2048 + t] = f2bf(v);
        }
      }
    }
  }
}

// ---------------------------------------------------------------------------
// Flash attention, causal.  q,k: [BH][T][64] bf16; v: [BH][64][T] bf16 (=V^T);
// y: [B][T][C] bf16.  S^T = K Q^T formulation: each lane owns one Q row per
// 16-tile (t = l16), so softmax reductions are 2 shuffles; P^T goes to the
// PV B-operand via register shuffles (no LDS round trip).  O^T = V^T P^T.
// launch_bounds (256,3): R3's (256,4) capped VGPRs at 64 -> massive scratch
// spill (WRITE_SIZE 150 MB vs 16 MB of output). Softmax runs in place on st.
__global__ __launch_bounds__(256, 3) void attn_kernel(const ushort* __restrict__ q,
                                                      const ushort* __restrict__ k,
                                                      const ushort* __restrict__ v,
                                                      ushort* __restrict__ y) {
  const int T = 2048;
  const int bh = blockIdx.y;            // 0..63
  const int qt = ((int)blockIdx.x + 4 * ((int)blockIdx.y >> 4)) & 15;  // CU load balance
  const int qbase = qt * 128;
  const int tid = threadIdx.x;
  const int lane = tid & 63, wave = tid >> 6;
  const int quad = lane >> 4, l16 = lane & 15;

  __shared__ ushort Qs[128][72];        // 18 KB
  __shared__ ushort Ks[64][72];         //  9 KB
  __shared__ ushort Vs[64][72];         //  9 KB (Vs[d][s])

  const ushort* qp = q + (size_t)bh * T * 64;
  const ushort* kp = k + (size_t)bh * T * 64;
  const ushort* vp = v + (size_t)bh * 64 * T;

  // stage Q tile (128 x 64)
#pragma unroll
  for (int it = 0; it < 4; ++it) {
    const int c = tid + it * 256;
    const int row = c >> 3, ko = (c & 7) * 8;
    *(uint4*)&Qs[row][ko] = *(const uint4*)(qp + (size_t)(qbase + row) * 64 + ko);
  }
  __syncthreads();

  // Q as B-operand frags (lane n=t=l16, k contiguous)
  bf16x8 aq[2][2];
#pragma unroll
  for (int i = 0; i < 2; ++i)
#pragma unroll
    for (int kk = 0; kk < 2; ++kk)
      aq[i][kk] = *(const bf16x8*)&Qs[wave * 32 + i * 16 + l16][kk * 32 + quad * 8];

  const f32x4 fzero = {0.f, 0.f, 0.f, 0.f};
  f32x4 acc_o[2][4];                    // O^T: [i-tile][jd], rows d=quad*4+r, col t=l16
  float mstate[2], lstate[2];
#pragma unroll
  for (int i = 0; i < 2; ++i) {
    mstate[i] = -1e30f; lstate[i] = 0.f;
#pragma unroll
    for (int jd = 0; jd < 4; ++jd) acc_o[i][jd] = fzero;
  }

  const int trow0 = qbase + wave * 32;
  const float SC = 0.125f * 1.4426950408889634f;  // (1/sqrt(64)) * log2(e)
  const int nkt = qt * 2 + 2;

  for (int kt = 0; kt < nkt; ++kt) {
    __syncthreads();
#pragma unroll
    for (int it = 0; it < 2; ++it) {
      const int c = tid + it * 256;
      const int row = c >> 3, ko = (c & 7) * 8;
      *(uint4*)&Ks[row][ko] = *(const uint4*)(kp + (size_t)(kt * 64 + row) * 64 + ko);
      *(uint4*)&Vs[row][ko] = *(const uint4*)(vp + (size_t)row * T + kt * 64 + ko);
    }
    __syncthreads();

    if (kt * 64 > trow0 + 31) continue;  // wave fully above diagonal for this K tile

    // K as A-operand frags (lane m=s=l16, k contiguous)
    bf16x8 ak[4][2];
#pragma unroll
    for (int j = 0; j < 4; ++j)
#pragma unroll
      for (int kk = 0; kk < 2; ++kk)
        ak[j][kk] = *(const bf16x8*)&Ks[j * 16 + l16][kk * 32 + quad * 8];

#pragma unroll
    for (int i = 0; i < 2; ++i) {
      const int tmin = trow0 + i * 16;
      if (kt * 64 > tmin + 15) continue;       // i-tile fully masked (wave-uniform)
      const int tglob = tmin + l16;            // this lane's Q row

      // S^T tile: D[m = s_local = j*16+quad*4+r][n = t = l16]
      f32x4 st[4];
#pragma unroll
      for (int j = 0; j < 4; ++j) st[j] = fzero;
#pragma unroll
      for (int j = 0; j < 4; ++j)
#pragma unroll
        for (int kk = 0; kk < 2; ++kk)
          st[j] = __builtin_amdgcn_mfma_f32_16x16x32_bf16(ak[j][kk], aq[i][kk], st[j], 0, 0, 0);

      // softmax over s (log2 domain), in place on st: lane owns row t = l16
      float mp = -1e30f;
      const bool needmask = (kt * 64 + 63 > tmin);  // wave-uniform
      if (needmask) {
#pragma unroll
        for (int j = 0; j < 4; ++j)
#pragma unroll
          for (int r = 0; r < 4; ++r) {
            const int sg = kt * 64 + j * 16 + quad * 4 + r;
            float xv = st[j][r] * SC;
            if (sg > tglob) xv = -1e30f;
            st[j][r] = xv;
            mp = fmaxf(mp, xv);
          }
      } else {
#pragma unroll
        for (int j = 0; j < 4; ++j)
#pragma unroll
          for (int r = 0; r < 4; ++r) {
            const float xv = st[j][r] * SC;
            st[j][r] = xv;
            mp = fmaxf(mp, xv);
          }
      }
      mp = fmaxf(mp, __shfl_xor(mp, 16, 64));
      mp = fmaxf(mp, __shfl_xor(mp, 32, 64));
      const float mnew = fmaxf(mstate[i], mp);
      const float alpha = exp2f(mstate[i] - mnew);
      mstate[i] = mnew;
      float rs = 0.f;
#pragma unroll
      for (int j = 0; j < 4; ++j)
#pragma unroll
        for (int r = 0; r < 4; ++r) {
          const float p = exp2f(st[j][r] - mnew);
          st[j][r] = p;
          rs += p;
        }
      rs += __shfl_xor(rs, 16, 64);
      rs += __shfl_xor(rs, 32, 64);
      lstate[i] = lstate[i] * alpha + rs;
#pragma unroll
      for (int jd = 0; jd < 4; ++jd) acc_o[i][jd] *= alpha;

      // pack P^T rows to bf16 pairs: pk[j][0]=(r0,r1), pk[j][1]=(r2,r3)
      uint32_t pk[4][2];
#pragma unroll
      for (int j = 0; j < 4; ++j) {
        pk[j][0] = pack2bf(st[j][0], st[j][1]);
        pk[j][1] = pack2bf(st[j][2], st[j][3]);
      }

      // build PV B-operand frags: lane (quad,l16) needs P^T[s=kk*32+quad*8+e][t=l16]
      union BU { uint32_t w[4]; bf16x8 h; } bu[2];
      const int L0 = ((quad & 1) << 5) + l16;
      const int L1 = L0 + 16;
#pragma unroll
      for (int kk = 0; kk < 2; ++kk) {
        const int jA = 2 * kk, jB = 2 * kk + 1;
        uint32_t a0 = (uint32_t)__shfl((int)pk[jA][0], L0, 64);
        uint32_t b0 = (uint32_t)__shfl((int)pk[jB][0], L0, 64);
        uint32_t a1 = (uint32_t)__shfl((int)pk[jA][1], L0, 64);
        uint32_t b1 = (uint32_t)__shfl((int)pk[jB][1], L0, 64);
        uint32_t a2 = (uint32_t)__shfl((int)pk[jA][0], L1, 64);
        uint32_t b2 = (uint32_t)__shfl((int)pk[jB][0], L1, 64);
        uint32_t a3 = (uint32_t)__shfl((int)pk[jA][1], L1, 64);
        uint32_t b3 = (uint32_t)__shfl((int)pk[jB][1], L1, 64);
        const bool lo = (quad < 2);
        bu[kk].w[0] = lo ? a0 : b0;
        bu[kk].w[1] = lo ? a1 : b1;
        bu[kk].w[2] = lo ? a2 : b2;
        bu[kk].w[3] = lo ? a3 : b3;
      }

      // O^T += V^T P^T  (V^T A-frags straight from Vs[d][s])
#pragma unroll
      for (int jd = 0; jd < 4; ++jd) {
        bf16x8 av0 = *(const bf16x8*)&Vs[jd * 16 + l16][quad * 8];
        bf16x8 av1 = *(const bf16x8*)&Vs[jd * 16 + l16][32 + quad * 8];
        acc_o[i][jd] = __builtin_amdgcn_mfma_f32_16x16x32_bf16(av0, bu[0].h, acc_o[i][jd], 0, 0, 0);
        acc_o[i][jd] = __builtin_amdgcn_mfma_f32_16x16x32_bf16(av1, bu[1].h, acc_o[i][jd], 0, 0, 0);
      }
    }
  }

  // epilogue: O^T C-layout: d = jd*16 + quad*4 + r, t = trow0 + i*16 + l16
  const int b = bh >> 4, h = bh & 15;
#pragma unroll
  for (int i = 0; i < 2; ++i) {
    const int t = trow0 + i * 16 + l16;
    const float inv = 1.0f / lstate[i];
#pragma unroll
    for (int jd = 0; jd < 4; ++jd) {
      uint2 w;
      w.x = pack2bf(acc_o[i][jd][0] * inv, acc_o[i][jd][1] * inv);
      w.y = pack2bf(acc_o[i][jd][2] * inv, acc_o[i][jd][3] * inv);
      *(uint2*)&y[((size_t)(b * 2048 + t)) * 1024 + h * 64 + jd * 16 + quad * 4] = w;
    }
  }
}

// ---------------------------------------------------------------------------
extern "C" void kernel_launch(void* const* d_in, const int* in_sizes, int n_in,
                              void* d_out, int out_size, void* d_ws, size_t ws_size,
                              hipStream_t stream) {
  const float* x  = (const float*)d_in[0];
  const float* Wq = (const float*)d_in[1];
  const float* bq = (const float*)d_in[2];
  const float* Wk = (const float*)d_in[3];
  const float* bk = (const float*)d_in[4];
  const float* Wv = (const float*)d_in[5];
  const float* bv = (const float*)d_in[6];
  const float* Wp = (const float*)d_in[7];
  const float* bp = (const float*)d_in[8];

  ushort* ws  = (ushort*)d_ws;
  ushort* wqt = ws;
  ushort* wkt = wqt + (size_t)1024 * 1024;
  ushort* wvt = wkt + (size_t)1024 * 1024;
  ushort* wpt = wvt + (size_t)1024 * 1024;
  ushort* xb  = wpt + (size_t)1024 * 1024;
  ushort* q   = xb + (size_t)8192 * 1024;
  ushort* kk  = q  + (size_t)8192 * 1024;
  ushort* vv  = kk + (size_t)8192 * 1024;
  ushort* y   = vv + (size_t)8192 * 1024;

  const dim3 tb(256);
  hipLaunchKernelGGL(f32_to_bf16, dim3(4096), tb, 0, stream, x, xb, 8192 * 1024);
  const dim3 tg(32, 32);
  hipLaunchKernelGGL(transpose_f32_bf16, tg, tb, 0, stream, Wq, wqt);
  hipLaunchKernelGGL(transpose_f32_bf16, tg, tb, 0, stream, Wk, wkt);
  hipLaunchKernelGGL(transpose_f32_bf16, tg, tb, 0, stream, Wv, wvt);
  hipLaunchKernelGGL(transpose_f32_bf16, tg, tb, 0, stream, Wp, wpt);

  const dim3 gg(8, 64);                 // N/128, M/128
  hipLaunchKernelGGL((gemm_bt<1>), gg, tb, 0, stream, xb, wqt, bq, (void*)q,  8192, 1024, 1024);
  hipLaunchKernelGGL((gemm_bt<1>), gg, tb, 0, stream, xb, wkt, bk, (void*)kk, 8192, 1024, 1024);
  hipLaunchKernelGGL((gemm_bt<2>), gg, tb, 0, stream, xb, wvt, bv, (void*)vv, 8192, 1024, 1024);

  const dim3 ag(16, 64);                // T/128, B*H
  hipLaunchKernelGGL(attn_kernel, ag, tb, 0, stream, q, kk, vv, y);

  hipLaunchKernelGGL((gemm_bt<0>), gg, tb, 0, stream, y, wpt, bp, d_out, 8192, 1024, 1024);
}